// Round 7
// baseline (466.696 us; speedup 1.0000x reference)
//
#include <hip/hip_runtime.h>
#include <hip/hip_bf16.h>
#include <hip/hip_fp16.h>
#include <math.h>

#define HID 128
#define EA 16
#define BM 64            // edges / nodes per block tile
#define FTP 136          // feat/out tile row stride (halfs)
#define EAP 40           // ea tile row stride (halfs)
#define PQP 136          // PQ/H tile row stride (halfs)
#define KT1 9            // W1 K-tiles (K padded 273 -> 288)
#define NC 8             // col blocks (128 / 16)
#define NTHREADS 256
#define GRIDM 1536       // 6 blocks/CU x 256 CUs

// workspace layout (bytes)
#define HIST_OFF   0                        // int[N]
#define WRPTR_OFF  (256*1024)               // int[N]
#define W1S_OFF    (512*1024)
#define W1S_ELEMS  (KT1 * NC * 64 * 8)      // 36864 fp16
#define W2S_OFF    (W1S_OFF + W1S_ELEMS * 2)
#define W2S_ELEMS  (4 * 64 * 8)             // 2048 fp16
#define SORTED_OFF (1024*1024)              // u64[E] = 8 MB
#define FEAT16_OFF (SORTED_OFF + 8*1024*1024)   // N*128 fp16 = 12.8 MB
#define P_OFF      (FEAT16_OFF + 13*1024*1024)  // N*128 fp16
#define Q_OFF      (P_OFF + 13*1024*1024)       // N*128 fp16

typedef _Float16 half8 __attribute__((ext_vector_type(8)));
typedef _Float16 half4v __attribute__((ext_vector_type(4)));
typedef float floatx4 __attribute__((ext_vector_type(4)));
typedef unsigned long long u64;

__device__ __forceinline__ float silu_f(float x) {
    return x * __builtin_amdgcn_rcpf(1.0f + __expf(-x));
}

// ---------------------------------------------------------------------------
// Prep: W1/W2 swizzle to fp16 fragment-linear, feat->fp16, zero seg,
// AND the row histogram (hist must be zeroed by the memset before this).
// ---------------------------------------------------------------------------
__global__ __launch_bounds__(NTHREADS, 4)
void prep_kernel(const float* __restrict__ W1,
                 const float* __restrict__ W2,
                 const float* __restrict__ node_feat,
                 const int*   __restrict__ edge_index,
                 _Float16* __restrict__ w1s,
                 _Float16* __restrict__ w2s,
                 _Float16* __restrict__ feat16,
                 float* __restrict__ seg,
                 int*   __restrict__ hist,
                 int nf8, int nseg, int E) {
    const int idx = blockIdx.x * NTHREADS + threadIdx.x;
    if (idx < W1S_ELEMS) {
        const int i    = idx & 7;
        const int lane = (idx >> 3) & 63;
        const int c    = (idx >> 9) & 7;
        const int kt   = idx >> 12;
        const int k    = kt * 32 + (lane >> 4) * 8 + i;
        const int n    = c * 16 + (lane & 15);
        float v = 0.0f;
        if (k < 273) {
            const int src = (k < 272) ? (k + 1) : 0;   // col-permuted: dist last
            v = W1[src * HID + n];
        }
        w1s[idx] = (_Float16)v;
    }
    if (idx < W2S_ELEMS) {
        const int i    = idx & 7;
        const int lane = (idx >> 3) & 63;
        const int kt   = idx >> 9;
        const int k    = kt * 32 + (lane >> 4) * 8 + i;
        const int n    = lane & 15;
        const float v  = (n < 3) ? W2[k * 3 + n] : 0.0f;
        w2s[idx] = (_Float16)v;
    }
    if (idx < nf8) {
        const float4* src = (const float4*)node_feat;
        const float4 a = src[2 * idx];
        const float4 b = src[2 * idx + 1];
        half8 h = { (_Float16)a.x, (_Float16)a.y, (_Float16)a.z, (_Float16)a.w,
                    (_Float16)b.x, (_Float16)b.y, (_Float16)b.z, (_Float16)b.w };
        ((half8*)feat16)[idx] = h;
    }
    if (idx < nseg) seg[idx] = 0.0f;
    if (idx < E) atomicAdd(hist + edge_index[idx], 1);
}

// single block, 1024 threads, serial chunk per thread (2 barriers total)
__global__ __launch_bounds__(1024, 1)
void scan_kernel(const int* __restrict__ hist,
                 int* __restrict__ wrptr, int N) {
    __shared__ int wsum[16];
    const int tid = threadIdx.x;
    const int C   = (N + 1023) >> 10;
    int lo = tid * C; if (lo > N) lo = N;
    int hi = lo + C;  if (hi > N) hi = N;
    int s = 0;
    for (int i = lo; i < hi; ++i) s += hist[i];
    const int lane = tid & 63, wid = tid >> 6;
    int v = s;
    #pragma unroll
    for (int d = 1; d < 64; d <<= 1) {
        const int t = __shfl_up(v, d, 64);
        if (lane >= d) v += t;
    }
    if (lane == 63) wsum[wid] = v;
    __syncthreads();
    if (tid == 0) {
        int a = 0;
        #pragma unroll
        for (int w = 0; w < 16; ++w) { const int t = wsum[w]; wsum[w] = a; a += t; }
    }
    __syncthreads();
    int run = wsum[wid] + v - s;
    for (int i = lo; i < hi; ++i) { wrptr[i] = run; run += hist[i]; }
}

// ---------------------------------------------------------------------------
// Fused: blocks [0, permBlocks) permute edges into row-sorted order;
// remaining blocks compute node-level GEMMs P = feat@W1_r, Q = feat@W1_c
// (two sequential accumulation passes -> low VGPR, no spill).
// ---------------------------------------------------------------------------
__global__ __launch_bounds__(NTHREADS, 2)
void permute_pq_kernel(const int* __restrict__ edge_index,
                       int* __restrict__ wrptr,
                       u64* __restrict__ sorted,
                       const _Float16* __restrict__ feat16,
                       const _Float16* __restrict__ w1s,
                       _Float16* __restrict__ P,
                       _Float16* __restrict__ Q,
                       int E, int N, int permBlocks) {
    __shared__ _Float16 ftile[BM][FTP];
    __shared__ _Float16 otile[BM][FTP];

    if (blockIdx.x < permBlocks) {
        const int e = blockIdx.x * NTHREADS + threadIdx.x;
        if (e < E) {
            const int row = edge_index[e];
            const int col = edge_index[(long)E + e];
            const int p   = atomicAdd(wrptr + row, 1);
            sorted[p] = ((u64)(unsigned)e << 32)
                      | ((u64)(unsigned short)col << 16)
                      | (u64)(unsigned short)row;
        }
        return;
    }

    const int tid  = threadIdx.x;
    const int base = (blockIdx.x - permBlocks) * BM;
    const int m    = tid >> 2;
    const int sub  = tid & 3;
    const int node = base + m;
    const int ncl  = node < N ? node : 0;

    const half8* fr = (const half8*)(feat16 + (long)ncl * HID);
    #pragma unroll
    for (int t = 0; t < 4; ++t)
        *(half8*)(&ftile[m][sub * 32 + t * 8]) = fr[sub * 4 + t];
    __syncthreads();

    const int wave = tid >> 6, lane = tid & 63, lrow = lane & 15, g = lane >> 4;
    const int c0 = 32 * wave + lrow, c1 = c0 + 16;

    // ---- P pass ----
    {
        floatx4 aP[4][2];
        #pragma unroll
        for (int rb = 0; rb < 4; ++rb) { aP[rb][0] = (floatx4){0,0,0,0}; aP[rb][1] = (floatx4){0,0,0,0}; }
        #pragma unroll
        for (int kt = 0; kt < 4; ++kt) {
            const half8 b0 = *(const half8*)(w1s + ((size_t)((kt * NC + 2*wave    ) * 64 + lane)) * 8);
            const half8 b1 = *(const half8*)(w1s + ((size_t)((kt * NC + 2*wave + 1) * 64 + lane)) * 8);
            #pragma unroll
            for (int rb = 0; rb < 4; ++rb) {
                const half8 af = *(const half8*)&ftile[16*rb + lrow][kt*32 + g*8];
                aP[rb][0] = __builtin_amdgcn_mfma_f32_16x16x32_f16(af, b0, aP[rb][0], 0, 0, 0);
                aP[rb][1] = __builtin_amdgcn_mfma_f32_16x16x32_f16(af, b1, aP[rb][1], 0, 0, 0);
            }
        }
        #pragma unroll
        for (int rb = 0; rb < 4; ++rb)
            #pragma unroll
            for (int reg = 0; reg < 4; ++reg) {
                const int r = 16*rb + 4*g + reg;
                otile[r][c0] = (_Float16)aP[rb][0][reg];
                otile[r][c1] = (_Float16)aP[rb][1][reg];
            }
        __syncthreads();
        if (node < N) {
            #pragma unroll
            for (int t = 0; t < 4; ++t)
                *(half8*)(P + (long)node * HID + sub * 32 + t * 8) = *(half8*)&otile[m][sub*32 + t*8];
        }
        __syncthreads();        // all otile reads done before Q pass overwrites
    }

    // ---- Q pass (ftile intact) ----
    {
        floatx4 aQ[4][2];
        #pragma unroll
        for (int rb = 0; rb < 4; ++rb) { aQ[rb][0] = (floatx4){0,0,0,0}; aQ[rb][1] = (floatx4){0,0,0,0}; }
        #pragma unroll
        for (int kt = 0; kt < 4; ++kt) {
            const half8 b0 = *(const half8*)(w1s + ((size_t)(((kt + 4) * NC + 2*wave    ) * 64 + lane)) * 8);
            const half8 b1 = *(const half8*)(w1s + ((size_t)(((kt + 4) * NC + 2*wave + 1) * 64 + lane)) * 8);
            #pragma unroll
            for (int rb = 0; rb < 4; ++rb) {
                const half8 af = *(const half8*)&ftile[16*rb + lrow][kt*32 + g*8];
                aQ[rb][0] = __builtin_amdgcn_mfma_f32_16x16x32_f16(af, b0, aQ[rb][0], 0, 0, 0);
                aQ[rb][1] = __builtin_amdgcn_mfma_f32_16x16x32_f16(af, b1, aQ[rb][1], 0, 0, 0);
            }
        }
        #pragma unroll
        for (int rb = 0; rb < 4; ++rb)
            #pragma unroll
            for (int reg = 0; reg < 4; ++reg) {
                const int r = 16*rb + 4*g + reg;
                otile[r][c0] = (_Float16)aQ[rb][0][reg];
                otile[r][c1] = (_Float16)aQ[rb][1][reg];
            }
        __syncthreads();
        if (node < N) {
            #pragma unroll
            for (int t = 0; t < 4; ++t)
                *(half8*)(Q + (long)node * HID + sub * 32 + t * 8) = *(half8*)&otile[m][sub*32 + t*8];
        }
    }
}

// ---------------------------------------------------------------------------
// Fused edge kernel over row-sorted edges.
// ---------------------------------------------------------------------------
__global__ __launch_bounds__(NTHREADS, 6)
void edge_kernel(
    const _Float16* __restrict__ Pp,       // [N][128] fp16
    const _Float16* __restrict__ Qp,       // [N][128] fp16
    const float* __restrict__ node_pos,    // [N][3]
    const float* __restrict__ edge_attr,   // [E][16]
    const float* __restrict__ b1,          // [128]
    const float* __restrict__ b2,          // [3]
    const u64*   __restrict__ sorted,      // [E] packed {e,col,row}
    const _Float16* __restrict__ w1s,
    const _Float16* __restrict__ w2s,
    float* __restrict__ seg,               // d_out [N][9]
    int E, int ntiles)
{
    __shared__ _Float16 eat[BM][EAP];      // cols 0..15 ea, 16 dist, 17..31 zero
    __shared__ _Float16 pq[BM][PQP];       // PQ sum, then H in place
    __shared__ float diffb[BM][4];
    __shared__ float wbuf[BM][3];
    __shared__ int   rowb[BM];

    const int tid  = threadIdx.x;
    const int m    = tid >> 2;
    const int sub  = tid & 3;
    const int wave = tid >> 6;
    const int lane = tid & 63;
    const int lrow = lane & 15;
    const int g    = lane >> 4;

    // hoisted B-fragments
    const half8 bW0 = *(const half8*)(w1s + ((size_t)((8 * NC + 2*wave    ) * 64 + lane)) * 8);
    const half8 bW1 = *(const half8*)(w1s + ((size_t)((8 * NC + 2*wave + 1) * 64 + lane)) * 8);
    half8 bw2[4];
    #pragma unroll
    for (int kt = 0; kt < 4; ++kt)
        bw2[kt] = *(const half8*)(w2s + ((size_t)(kt * 64 + lane)) * 8);
    const int col0 = 32 * wave + lrow, col1 = col0 + 16;
    const float bb0 = b1[col0], bb1 = b1[col1];

    for (int tile = blockIdx.x; tile < ntiles; tile += GRIDM) {
        __syncthreads();                       // (A) prev tile consumers done

        // ---- staging: PQ gather-sum (packed fp16 adds), ea, pos ----
        {
            const long p  = (long)tile * BM + m;
            const long pc = p < E ? p : (long)(E - 1);
            const u64 pk  = sorted[pc];
            const int row = (int)(pk & 0xffff);
            const int cn  = (int)((pk >> 16) & 0xffff);
            const unsigned e = (unsigned)(pk >> 32);

            const half8* Pr = (const half8*)(Pp + (long)row * HID);
            const half8* Qc = (const half8*)(Qp + (long)cn * HID);
            #pragma unroll
            for (int t = 0; t < 4; ++t) {
                const half8 a = Pr[sub * 4 + t];
                const half8 b = Qc[sub * 4 + t];
                *(half8*)(&pq[m][sub * 32 + t * 8]) = a + b;   // v_pk_add_f16
            }
            const float4 ea = ((const float4*)(edge_attr + (long)e * EA))[sub];
            half4v h4 = { (_Float16)ea.x, (_Float16)ea.y, (_Float16)ea.z, (_Float16)ea.w };
            *(half4v*)(&eat[m][sub * 4]) = h4;
            if (sub == 0) {
                rowb[m] = row;
                const float dx = node_pos[row*3+0] - node_pos[cn*3+0];
                const float dy = node_pos[row*3+1] - node_pos[cn*3+1];
                const float dz = node_pos[row*3+2] - node_pos[cn*3+2];
                const float dist = sqrtf(dx*dx + dy*dy + dz*dz);
                diffb[m][0] = dx; diffb[m][1] = dy; diffb[m][2] = dz; diffb[m][3] = dist;
                half8 z = { (_Float16)dist, (_Float16)0.f, (_Float16)0.f, (_Float16)0.f,
                            (_Float16)0.f, (_Float16)0.f, (_Float16)0.f, (_Float16)0.f };
                *(half8*)(&eat[m][16]) = z;
            } else if (sub == 1) {
                half8 z = { (_Float16)0.f, (_Float16)0.f, (_Float16)0.f, (_Float16)0.f,
                            (_Float16)0.f, (_Float16)0.f, (_Float16)0.f, (_Float16)0.f };
                *(half8*)(&eat[m][24]) = z;
            }
        }
        __syncthreads();                       // (B) tiles ready

        // ---- GEMM1: {ea,dist} @ W1e — 8 MFMAs ----
        floatx4 acc[4][2];
        #pragma unroll
        for (int rb = 0; rb < 4; ++rb) {
            acc[rb][0] = (floatx4){0,0,0,0};
            acc[rb][1] = (floatx4){0,0,0,0};
        }
        #pragma unroll
        for (int rb = 0; rb < 4; ++rb) {
            const half8 af = *(const half8*)&eat[16*rb + lrow][g * 8];
            acc[rb][0] = __builtin_amdgcn_mfma_f32_16x16x32_f16(af, bW0, acc[rb][0], 0, 0, 0);
            acc[rb][1] = __builtin_amdgcn_mfma_f32_16x16x32_f16(af, bW1, acc[rb][1], 0, 0, 0);
        }

        // ---- epilogue: h = silu(acc + PQ + b1), H written in place ----
        #pragma unroll
        for (int rb = 0; rb < 4; ++rb)
            #pragma unroll
            for (int reg = 0; reg < 4; ++reg) {
                const int r = 16*rb + 4*g + reg;
                const float h0 = silu_f(acc[rb][0][reg] + (float)pq[r][col0] + bb0);
                const float h1 = silu_f(acc[rb][1][reg] + (float)pq[r][col1] + bb1);
                pq[r][col0] = (_Float16)h0;
                pq[r][col1] = (_Float16)h1;
            }
        __syncthreads();                       // (D) H complete

        // ---- GEMM2: w = silu(H @ W2 + b2) ----
        {
            floatx4 acc2 = (floatx4){0,0,0,0};
            #pragma unroll
            for (int kt = 0; kt < 4; ++kt) {
                const half8 af = *(const half8*)&pq[16*wave + lrow][kt*32 + g*8];
                acc2 = __builtin_amdgcn_mfma_f32_16x16x32_f16(af, bw2[kt], acc2, 0, 0, 0);
            }
            if (lrow < 3) {
                const float bb2 = b2[lrow];
                #pragma unroll
                for (int reg = 0; reg < 4; ++reg)
                    wbuf[16*wave + 4*g + reg][lrow] = silu_f(acc2[reg] + bb2);
            }
        }
        __syncthreads();                       // (E)

        // ---- SH + segmented scan, all 4 waves (wave w owns 2-3 components) ----
        {
            const long p0 = (long)tile * BM;
            const bool valid = (p0 + lane) < E;
            int rw = valid ? rowb[lane] : -1;

            const float dx = diffb[lane][0], dy = diffb[lane][1], dz = diffb[lane][2];
            const float dist = diffb[lane][3];
            const float inv = __builtin_amdgcn_rcpf(fmaxf(dist, 1e-12f));
            const float x = dx * inv, y = dy * inv, z = dz * inv;
            const float s3 = 1.7320508075688772f;

            float v0, v1, v2 = 0.0f;
            int cA, cB;
            if (wave == 0) {
                const float w0 = wbuf[lane][0], w2v = wbuf[lane][2];
                v0 = w0;  v1 = s3 * x * z * w2v;  v2 = 0.5f * s3 * (z*z - x*x) * w2v;
                cA = 0; cB = 4;
            } else if (wave == 1) {
                const float w1v = wbuf[lane][1], w2v = wbuf[lane][2];
                v0 = x * w1v;  v1 = s3 * x * y * w2v;
                cA = 1; cB = 5;
            } else if (wave == 2) {
                const float w1v = wbuf[lane][1], w2v = wbuf[lane][2];
                v0 = y * w1v;  v1 = (y*y - 0.5f*(x*x + z*z)) * w2v;
                cA = 2; cB = 6;
            } else {
                const float w1v = wbuf[lane][1], w2v = wbuf[lane][2];
                v0 = z * w1v;  v1 = s3 * y * z * w2v;
                cA = 3; cB = 7;
            }
            if (!valid) { v0 = 0.0f; v1 = 0.0f; v2 = 0.0f; }

            const int rprev = __shfl_up(rw, 1, 64);
            int fl = (lane == 0 || rw != rprev) ? 1 : 0;
            #pragma unroll
            for (int d = 1; d < 64; d <<= 1) {
                const int   fo = __shfl_up(fl, d, 64);
                const float a0 = __shfl_up(v0, d, 64);
                const float a1 = __shfl_up(v1, d, 64);
                const float a2 = __shfl_up(v2, d, 64);
                if (lane >= d && !fl) { v0 += a0; v1 += a1; v2 += a2; }
                if (lane >= d) fl |= fo;
            }
            const int rnext = __shfl_down(rw, 1, 64);
            const bool endseg = (lane == 63) || (rw != rnext);
            if (endseg && rw >= 0) {
                float* o = seg + (long)rw * 9;
                atomicAdd(o + cA, v0);
                atomicAdd(o + cB, v1);
                if (wave == 0) atomicAdd(o + 8, v2);
            }
        }
    }
}

__global__ void finalize_kernel(float* __restrict__ out,
                                const int* __restrict__ hist, int n_out) {
    const int i = blockIdx.x * blockDim.x + threadIdx.x;
    if (i < n_out) {
        const float c = (float)hist[i / 9];
        out[i] = out[i] / fmaxf(c, 1.0f);
    }
}

extern "C" void kernel_launch(void* const* d_in, const int* in_sizes, int n_in,
                              void* d_out, int out_size, void* d_ws, size_t ws_size,
                              hipStream_t stream) {
    const float* node_feat  = (const float*)d_in[0];
    const float* node_pos   = (const float*)d_in[1];
    const float* edge_attr  = (const float*)d_in[2];
    const float* W1         = (const float*)d_in[3];
    const float* b1         = (const float*)d_in[4];
    const float* W2         = (const float*)d_in[5];
    const float* b2         = (const float*)d_in[6];
    const int*   edge_index = (const int*)d_in[7];

    const int E = in_sizes[7] / 2;
    const int N = in_sizes[1] / 3;
    const int ntiles = (E + BM - 1) / BM;

    char* ws = (char*)d_ws;
    float*    seg    = (float*)d_out;
    int*      hist   = (int*)(ws + HIST_OFF);
    int*      wrptr  = (int*)(ws + WRPTR_OFF);
    _Float16* w1s    = (_Float16*)(ws + W1S_OFF);
    _Float16* w2s    = (_Float16*)(ws + W2S_OFF);
    u64*      sorted = (u64*)(ws + SORTED_OFF);
    _Float16* feat16 = (_Float16*)(ws + FEAT16_OFF);
    _Float16* Pp     = (_Float16*)(ws + P_OFF);
    _Float16* Qp     = (_Float16*)(ws + Q_OFF);

    hipMemsetAsync(hist, 0, (size_t)N * sizeof(int), stream);

    const int nf8 = N * HID / 8;
    int nprep = nf8 > out_size ? nf8 : out_size;
    if (nprep < W1S_ELEMS) nprep = W1S_ELEMS;
    if (nprep < E) nprep = E;
    prep_kernel<<<(nprep + NTHREADS - 1) / NTHREADS, NTHREADS, 0, stream>>>(
        W1, W2, node_feat, edge_index, w1s, w2s, feat16, seg, hist,
        nf8, out_size, E);

    scan_kernel<<<1, 1024, 0, stream>>>(hist, wrptr, N);

    const int permBlocks = (E + NTHREADS - 1) / NTHREADS;
    const int pqBlocks   = (N + BM - 1) / BM;
    permute_pq_kernel<<<permBlocks + pqBlocks, NTHREADS, 0, stream>>>(
        edge_index, wrptr, sorted, feat16, w1s, Pp, Qp, E, N, permBlocks);

    edge_kernel<<<GRIDM, NTHREADS, 0, stream>>>(
        Pp, Qp, node_pos, edge_attr, b1, b2, sorted, w1s, w2s, seg, E, ntiles);

    const int nfin = (out_size + 255) / 256;
    finalize_kernel<<<nfin, 256, 0, stream>>>(seg, hist, out_size);
}